// Round 16
// baseline (115.377 us; speedup 1.0000x reference)
//
#include <hip/hip_runtime.h>
#include <math.h>

typedef unsigned short ushort_t;
typedef __attribute__((ext_vector_type(8))) short bf16x8;
typedef __attribute__((ext_vector_type(16))) float f32x16;

__device__ __forceinline__ ushort_t f2bf(float f) {
    unsigned u = __float_as_uint(f);
    u += 0x7fffu + ((u >> 16) & 1u);          // RNE
    return (ushort_t)(u >> 16);
}
__device__ __forceinline__ float bf2f(ushort_t h) {
    return __uint_as_float(((unsigned)h) << 16);
}

// ---------------------------------------------------------------------------
// Halo-zero helper for planar padded bf16 buffer [2][160][HP][HP][32].
// ---------------------------------------------------------------------------
template <int HP>
__device__ __forceinline__ void zero_halo(ushort_t* buf, int n, int t, int nthr)
{
    const size_t PSTR = (size_t)160 * HP * HP * 32;
    constexpr int W = HP - 2;
    constexpr int NB = 2 * HP + 2 * W;
    for (int j = t; j < 2 * NB; j += nthr) {
        const int pl = j / NB, i = j % NB;
        int yy, xx;
        if (i < HP)            { yy = 0;            xx = i; }
        else if (i < 2 * HP)   { yy = HP - 1;       xx = i - HP; }
        else if (i < 2*HP + W) { yy = i - 2*HP + 1; xx = 0; }
        else                   { yy = i - 2*HP - W + 1; xx = HP - 1; }
        uint4* p = (uint4*)(buf + pl * PSTR +
                            ((size_t)n * HP * HP + yy * HP + xx) * 32);
        const uint4 z = make_uint4(0u, 0u, 0u, 0u);
        p[0] = z; p[1] = z;
    }
}

// ---------------------------------------------------------------------------
// prep_k: fused input pack + weight pack + halo zeroing + embv zeroing.
//  b in [0,160): pack image; [160,167): weights; [167,327): halos; 327: embv=0
// ---------------------------------------------------------------------------
__global__ __launch_bounds__(256) void prep_k(
    const float* __restrict__ q, const float* __restrict__ s,
    const float* __restrict__ w1, const float* __restrict__ w2,
    const float* __restrict__ w3, const float* __restrict__ w4,
    ushort_t* __restrict__ p0, ushort_t* __restrict__ pw1,
    ushort_t* __restrict__ pw234,
    ushort_t* __restrict__ P1, ushort_t* __restrict__ P2,
    ushort_t* __restrict__ P3, float* __restrict__ embv)
{
    const int b = blockIdx.x, t = threadIdx.x;
    if (b < 160) {
        const int n = b;
        const float* src; int nn;
        if (n < 60) { src = q; nn = n; } else { src = s; nn = n - 60; }
        const float* img = src + (size_t)nn * 3 * 7056;
        for (int px = t; px < 7396; px += 256) {
            const int y = px / 86, x = px % 86;
            uint4 v = make_uint4(0u, 0u, 0u, 0u);
            if (y >= 1 && y <= 84 && x >= 1 && x <= 84) {
                const int o = (y - 1) * 84 + (x - 1);
                const unsigned c0 = f2bf(img[o]);
                const unsigned c1 = f2bf(img[7056 + o]);
                const unsigned c2 = f2bf(img[14112 + o]);
                v.x = c0 | (c1 << 16);
                v.y = c2;
            }
            *(uint4*)(p0 + ((size_t)n * 7396 + px) * 8) = v;
        }
    } else if (b < 167) {
        const int bw = b - 160;
        if (bw == 0) {
            for (int idx = t; idx < 5120; idx += 256) {
                const int sl = idx >> 10, rem = idx & 1023;
                const int co = rem >> 4, c = rem & 15;
                const int h = c >> 3, e = c & 7, tap = 2 * sl + h;
                float v = 0.f;
                if (tap < 9 && e < 3) v = w1[co * 27 + e * 9 + tap];
                pw1[idx] = f2bf(v);
            }
        } else {
            const int l = (bw - 1) >> 1, pass = (bw - 1) & 1;
            const float* w = (l == 0) ? w2 : (l == 1) ? w3 : w4;
            ushort_t* dst = pw234 + l * 36864 + pass * 18432;
            for (int idx = t; idx < 18432; idx += 256) {
                const int c  = idx & 7;
                const int co = (idx >> 3) & 63;
                const int h  = (idx >> 9) & 1;
                const int kl = (idx >> 10) & 1;
                const int tap = idx >> 11;
                const int ci = pass * 32 + kl * 16 + h * 8 + c;
                dst[idx] = f2bf(w[co * 576 + ci * 9 + tap]);
            }
        }
    } else if (b < 327) {
        const int n = b - 167;
        zero_halo<44>(P1, n, t, 256);
        zero_halo<23>(P2, n, t, 256);
        zero_halo<23>(P3, n, t, 256);
    } else {
        // zero emb accumulator (160*64 f32) every call
        for (int i = t; i < 2560; i += 256)
            ((uint4*)embv)[i] = make_uint4(0u, 0u, 0u, 0u);
    }
}

// ---------------------------------------------------------------------------
// conv1 LDS fat-strip MFMA (unchanged, proven).
// ---------------------------------------------------------------------------
__global__ __launch_bounds__(256, 2) void conv1_lds_k(
    const ushort_t* __restrict__ p0, const ushort_t* __restrict__ pw1,
    const float* __restrict__ gg, const float* __restrict__ bb,
    ushort_t* __restrict__ outp)
{
    constexpr int ROWB = 86 * 16 + 16;   // 1392 B
    constexpr int R = 6;
    constexpr int PXB = 84;              // pooled px per strip
    constexpr size_t PLANE1 = (size_t)160 * 1936 * 32;

    __shared__ __align__(16) char alds[R * ROWB];
    __shared__ __align__(16) char blds[10240];

    const int tid = threadIdx.x, wv = tid >> 6, lane = tid & 63;
    const int l31 = lane & 31, h = lane >> 5;
    const int s = blockIdx.x, n = blockIdx.y;
    const int row0 = 4 * s;

    int abase[3];
#pragma unroll
    for (int t = 0; t < 3; ++t) {
        const int ml = wv * 96 + t * 32 + l31;
        int pp = ml >> 2; if (pp > PXB - 1) pp = PXB - 1;
        const int qd = ml & 3;
        const int p = PXB * s + pp;
        const int pr = p / 42, pc = p % 42;
        const int yl = 2 * (pr - 2 * s) + (qd >> 1);
        const int xl = 2 * pc + (qd & 1);
        abase[t] = yl * ROWB + xl * 16;
    }
    int boff[2];
#pragma unroll
    for (int nt = 0; nt < 2; ++nt) boff[nt] = (nt * 32 + l31) * 32 + h * 16;

    {
        const uint4* src = (const uint4*)(p0 + (size_t)n * 7396 * 8);
        for (int i = tid; i < R * 86; i += 256) {
            const int y = i / 86, x = i - y * 86;
            *(uint4*)(alds + y * ROWB + x * 16) = src[(row0 + y) * 86 + x];
        }
    }
    for (int i = tid; i < 640; i += 256)
        ((uint4*)blds)[i] = ((const uint4*)pw1)[i];

    f32x16 acc[3][2];
#pragma unroll
    for (int t = 0; t < 3; ++t)
#pragma unroll
        for (int nt = 0; nt < 2; ++nt)
#pragma unroll
            for (int r = 0; r < 16; ++r) acc[t][nt][r] = 0.f;

    __syncthreads();

#pragma unroll
    for (int st = 0; st < 5; ++st) {
        int tap = 2 * st + h;
        if (tap > 8) tap = 8;           // B is zero there; data unused
        const int imm = (tap / 3) * ROWB + (tap % 3) * 16;
        const bf16x8 a0 = *(const bf16x8*)(alds + abase[0] + imm);
        const bf16x8 a1 = *(const bf16x8*)(alds + abase[1] + imm);
        const bf16x8 a2 = *(const bf16x8*)(alds + abase[2] + imm);
#pragma unroll
        for (int nt = 0; nt < 2; ++nt) {
            const bf16x8 b = *(const bf16x8*)(blds + st * 2048 + boff[nt]);
            acc[0][nt] = __builtin_amdgcn_mfma_f32_32x32x16_bf16(
                a0, b, acc[0][nt], 0, 0, 0);
            acc[1][nt] = __builtin_amdgcn_mfma_f32_32x32x16_bf16(
                a1, b, acc[1][nt], 0, 0, 0);
            acc[2][nt] = __builtin_amdgcn_mfma_f32_32x32x16_bf16(
                a2, b, acc[2][nt], 0, 0, 0);
        }
    }

    float gv2[2], bv2[2];
#pragma unroll
    for (int nt = 0; nt < 2; ++nt) {
        gv2[nt] = gg[nt * 32 + l31];
        bv2[nt] = bb[nt * 32 + l31];
    }
#pragma unroll
    for (int t = 0; t < 3; ++t) {
#pragma unroll
        for (int g = 0; g < 4; ++g) {
            const int mbase = wv * 96 + t * 32 + 8 * g + 4 * h;
            const int pp = mbase >> 2;
            if (pp >= PXB) continue;
            const int p = PXB * s + pp;
            const int pr = p / 42, pc = p % 42;
            ushort_t* dpix =
                outp + ((size_t)n * 1936 + (pr + 1) * 44 + (pc + 1)) * 32 + l31;
#pragma unroll
            for (int nt = 0; nt < 2; ++nt) {
                float mx = 0.f;   // ReLU lower bound
#pragma unroll
                for (int qd = 0; qd < 4; ++qd)
                    mx = fmaxf(mx, fmaf(acc[t][nt][4 * g + qd], gv2[nt], bv2[nt]));
                dpix[nt * PLANE1] = f2bf(mx);
            }
        }
    }
}

// ---------------------------------------------------------------------------
// LDS-A + ring-4 global-B MFMA conv 3x3 (proven structure).
// EPI: 0 = affine+ReLU+2x2pool -> planar padded, 1 = planar padded write,
//      2 = fused global-average-pool: atomicAdd f32 emb (outp = float* emb).
// ---------------------------------------------------------------------------
template <int HINP, int POOL, int EPI, int RPB, int WAVES>
__device__ __forceinline__ void conv_body(
    const ushort_t* __restrict__ act, const ushort_t* __restrict__ pkw,
    const float* __restrict__ gg, const float* __restrict__ bb,
    ushort_t* __restrict__ outp)
{
    constexpr int MT   = 2;
    constexpr int NTHR = WAVES * 64;
    constexpr int PXB  = 21 * RPB;
    constexpr int R    = POOL ? 2 * RPB + 2 : RPB + 2;
    constexpr int ROWB = HINP * 80;
    const size_t APLANE = (size_t)160 * HINP * HINP * 32;
    constexpr size_t OPLANE = (size_t)160 * 529 * 32;

    __shared__ __align__(16) char alds[R * ROWB];

    const int tid = threadIdx.x, wv = tid >> 6, lane = tid & 63;
    const int l31 = lane & 31, h = lane >> 5;
    const int s = blockIdx.x, n = blockIdx.y;

    const int row0 = POOL ? 2 * RPB * s : RPB * s;

    int abase[MT];
#pragma unroll
    for (int t = 0; t < MT; ++t) {
        const int ml = wv * (MT * 32) + t * 32 + l31;
        int yl, xl;
        if (POOL) {
            int pp = ml >> 2; if (pp > PXB - 1) pp = PXB - 1;
            int p = PXB * s + pp; if (p > 440) p = 440;
            const int qd = ml & 3;
            yl = 2 * (p / 21 - RPB * s) + (qd >> 1);
            xl = 2 * (p % 21) + (qd & 1);
        } else {
            int pp = ml; if (pp > PXB - 1) pp = PXB - 1;
            int p = PXB * s + pp; if (p > 440) p = 440;
            yl = p / 21 - RPB * s;
            xl = p % 21;
        }
        abase[t] = yl * ROWB + xl * 80 + h * 16;
    }
    int boff[2];
#pragma unroll
    for (int nt = 0; nt < 2; ++nt) boff[nt] = h * 1024 + (nt * 32 + l31) * 16;

    f32x16 acc[MT][2];
#pragma unroll
    for (int t = 0; t < MT; ++t)
#pragma unroll
        for (int nt = 0; nt < 2; ++nt)
#pragma unroll
            for (int r = 0; r < 16; ++r) acc[t][nt][r] = 0.f;

    bf16x8 br[4][2];   // ring-4 B [slot][nt], statically indexed

#define B_LD(S, SLOT)                                                      \
    {                                                                      \
        br[SLOT][0] = *(const bf16x8*)(bg + (S)*2048 + boff[0]);           \
        br[SLOT][1] = *(const bf16x8*)(bg + (S)*2048 + boff[1]);           \
    }

    for (int ph = 0; ph < 2; ++ph) {
        const char* bg = (const char*)pkw + ph * 36864;
        // issue first 4 B-step loads; they fly during A staging + barrier
        B_LD(0, 0) B_LD(1, 1) B_LD(2, 2) B_LD(3, 3)

        if (ph) __syncthreads();
        // ---- stage A strip (coalesced 64B/thread-px global reads) ----
        {
            const uint4* src = (const uint4*)(act +
                (ph * APLANE + (size_t)n * HINP * HINP * 32));
            for (int p = tid; p < R * HINP; p += NTHR) {
                const int y = p / HINP, x = p - y * HINP;
                const int row = min(row0 + y, HINP - 1);
                const uint4* sp = src + ((size_t)row * HINP + x) * 4;
                const uint4 c0 = sp[0], c1 = sp[1], c2 = sp[2], c3 = sp[3];
                char* d = alds + y * ROWB + x * 80;
                *(uint4*)(d)      = c0;
                *(uint4*)(d + 16) = c1;
                *(uint4*)(d + 32) = c2;
                *(uint4*)(d + 48) = c3;
            }
        }
        __syncthreads();

        // ---- 18-step K loop: A from LDS, B ring-4 from global ----
#pragma unroll
        for (int st = 0; st < 18; ++st) {
            const int sl = st & 3;
            const int tap = st >> 1, kl = st & 1;
            const int imm = (tap / 3) * ROWB + (tap % 3) * 80 + kl * 32;
            const bf16x8 a0 = *(const bf16x8*)(alds + abase[0] + imm);
            const bf16x8 a1 = *(const bf16x8*)(alds + abase[1] + imm);
            const bf16x8 b0 = br[sl][0];
            const bf16x8 b1 = br[sl][1];
            if (st < 14) B_LD(st + 4, sl)
            acc[0][0] = __builtin_amdgcn_mfma_f32_32x32x16_bf16(
                a0, b0, acc[0][0], 0, 0, 0);
            acc[1][0] = __builtin_amdgcn_mfma_f32_32x32x16_bf16(
                a1, b0, acc[1][0], 0, 0, 0);
            acc[0][1] = __builtin_amdgcn_mfma_f32_32x32x16_bf16(
                a0, b1, acc[0][1], 0, 0, 0);
            acc[1][1] = __builtin_amdgcn_mfma_f32_32x32x16_bf16(
                a1, b1, acc[1][1], 0, 0, 0);
        }
    }
#undef B_LD

    // ---- epilogue ----
    float gv2[2], bv2[2];
#pragma unroll
    for (int nt = 0; nt < 2; ++nt) {
        gv2[nt] = gg[nt * 32 + l31];
        bv2[nt] = bb[nt * 32 + l31];
    }

    if (EPI == 0) {
#pragma unroll
        for (int t = 0; t < MT; ++t) {
#pragma unroll
            for (int g = 0; g < 4; ++g) {
                const int mbase = wv * (MT * 32) + t * 32 + 8 * g + 4 * h;
                const int pp = mbase >> 2;
                const int p_img = PXB * s + pp;
                if (pp >= PXB || p_img >= 441) continue;
                const int py = p_img / 21, px = p_img % 21;
                ushort_t* dpix = outp +
                    ((size_t)n * 529 + (py + 1) * 23 + (px + 1)) * 32 + l31;
#pragma unroll
                for (int nt = 0; nt < 2; ++nt) {
                    float mx = 0.f;
#pragma unroll
                    for (int qd = 0; qd < 4; ++qd)
                        mx = fmaxf(mx,
                                   fmaf(acc[t][nt][4 * g + qd], gv2[nt], bv2[nt]));
                    dpix[nt * OPLANE] = f2bf(mx);
                }
            }
        }
    } else if (EPI == 1) {
#pragma unroll
        for (int t = 0; t < MT; ++t) {
#pragma unroll
            for (int r = 0; r < 16; ++r) {
                const int mloc = wv * (MT * 32) + t * 32 +
                                 (r & 3) + 8 * (r >> 2) + 4 * h;
                const int m_img = PXB * s + mloc;
                if (mloc >= PXB || m_img >= 441) continue;
                const int y = m_img / 21, x = m_img % 21;
#pragma unroll
                for (int nt = 0; nt < 2; ++nt) {
                    const float v =
                        fmaxf(fmaf(acc[t][nt][r], gv2[nt], bv2[nt]), 0.f);
                    outp[nt * OPLANE +
                         ((size_t)n * 529 + (y + 1) * 23 + (x + 1)) * 32 + l31] =
                        f2bf(v);
                }
            }
        }
    } else {
        // EPI==2: fused global average pool -> atomicAdd into f32 emb
        float* embf = (float*)outp;
#pragma unroll
        for (int nt = 0; nt < 2; ++nt) {
            float sum = 0.f;
#pragma unroll
            for (int t = 0; t < MT; ++t) {
#pragma unroll
                for (int r = 0; r < 16; ++r) {
                    const int mloc = wv * (MT * 32) + t * 32 +
                                     (r & 3) + 8 * (r >> 2) + 4 * h;
                    const int m_img = PXB * s + mloc;
                    if (mloc < PXB && m_img < 441)
                        sum += fmaxf(fmaf(acc[t][nt][r], gv2[nt], bv2[nt]), 0.f);
                }
            }
            atomicAdd(&embf[(size_t)n * 64 + nt * 32 + l31],
                      sum * (1.f / 441.f));
        }
    }
}

// conv2: 4-wave 256-thr, MT=2, RPB=3. LDS 28,160B; (256,4) -> 4 blocks/CU
// (VGPR body measured 88 <= 128 budget; 4x28.2KB = 112.6KB LDS).
__global__ __launch_bounds__(256, 4) void conv2_k(
    const ushort_t* __restrict__ act, const ushort_t* __restrict__ pkw,
    const float* __restrict__ gg, const float* __restrict__ bb,
    ushort_t* __restrict__ outp)
{ conv_body<44, 1, 0, 3, 4>(act, pkw, gg, bb, outp); }

// conv3/4: 2-wave 128-thr, MT=2, RPB=6. LDS 14.7KB (already all-resident).
__global__ __launch_bounds__(128, 3) void conv3_k(
    const ushort_t* __restrict__ act, const ushort_t* __restrict__ pkw,
    const float* __restrict__ gg, const float* __restrict__ bb,
    ushort_t* __restrict__ outp)
{ conv_body<23, 0, 1, 6, 2>(act, pkw, gg, bb, outp); }

__global__ __launch_bounds__(128, 3) void conv4_k(
    const ushort_t* __restrict__ act, const ushort_t* __restrict__ pkw,
    const float* __restrict__ gg, const float* __restrict__ bb,
    ushort_t* __restrict__ outp)   // outp = (ushort_t*)embv (f32 accumulator)
{ conv_body<23, 0, 2, 6, 2>(act, pkw, gg, bb, outp); }

// ---------------------------------------------------------------------------
// Relation head.
// ---------------------------------------------------------------------------
__global__ __launch_bounds__(64) void relation_k(
    const float* __restrict__ emb,
    const float* __restrict__ fc1w, const float* __restrict__ fc1b,
    const float* __restrict__ fc2w, const float* __restrict__ fc2b,
    const float* __restrict__ fc3w, const float* __restrict__ fc3b,
    float* __restrict__ out)
{
    const int idx = blockIdx.x;
    const int w = idx % 5;
    const int bq = idx / 5;
    const int b = bq / 15;
    const int t = threadIdx.x;

    __shared__ float dif[64], h1v[64], h2v[32];
    const float qv = emb[(size_t)bq * 64 + t];

    float ssum = 0.f;
    for (int s = 0; s < 5; ++s) {
        const int simg = 60 + ((b * 5 + w) * 5 + s);
        __syncthreads();
        dif[t] = fabsf(qv - emb[(size_t)simg * 64 + t]);
        __syncthreads();
        float a = fc1b[t];
        for (int d = 0; d < 64; ++d) a = fmaf(fc1w[t * 64 + d], dif[d], a);
        a = fmaxf(a, 0.f);
        __syncthreads();
        h1v[t] = a;
        __syncthreads();
        if (t < 32) {
            float h = fc2b[t];
            for (int d = 0; d < 64; ++d) h = fmaf(fc2w[t * 64 + d], h1v[d], h);
            h2v[t] = fmaxf(h, 0.f);
        }
        __syncthreads();
        float p = (t < 32) ? fc3w[t] * h2v[t] : 0.f;
#pragma unroll
        for (int off = 32; off > 0; off >>= 1) p += __shfl_down(p, off);
        if (t == 0) {
            const float z = p + fc3b[0];
            ssum += 1.f / (1.f + expf(-z));
        }
    }
    if (t == 0) out[idx] = ssum * 0.2f;
}

// ---------------------------------------------------------------------------
extern "C" void kernel_launch(void* const* d_in, const int* in_sizes, int n_in,
                              void* d_out, int out_size, void* d_ws, size_t ws_size,
                              hipStream_t stream)
{
    const float* q    = (const float*)d_in[0];
    const float* s    = (const float*)d_in[1];
    const float* w1   = (const float*)d_in[2];
    const float* g1   = (const float*)d_in[3];
    const float* b1p  = (const float*)d_in[4];
    const float* w2   = (const float*)d_in[5];
    const float* g2   = (const float*)d_in[6];
    const float* b2p  = (const float*)d_in[7];
    const float* w3   = (const float*)d_in[8];
    const float* g3   = (const float*)d_in[9];
    const float* b3p  = (const float*)d_in[10];
    const float* w4   = (const float*)d_in[11];
    const float* g4   = (const float*)d_in[12];
    const float* b4p  = (const float*)d_in[13];
    const float* fc1w = (const float*)d_in[14];
    const float* fc1b = (const float*)d_in[15];
    const float* fc2w = (const float*)d_in[16];
    const float* fc2b = (const float*)d_in[17];
    const float* fc3w = (const float*)d_in[18];
    const float* fc3b = (const float*)d_in[19];
    float* out = (float*)d_out;

    char* ws = (char*)d_ws;
    ushort_t* P0    = (ushort_t*)(ws + 0);          // 18,933,760
    ushort_t* P1    = (ushort_t*)(ws + 18933760);   // 39,649,280
    ushort_t* P2    = (ushort_t*)(ws + 58583040);   // 10,833,920
    ushort_t* P3    = (ushort_t*)(ws + 69416960);   // 10,833,920
    float*    embv  = (float*)   (ws + 80250880);   // 40,960 (f32 accumulator)
    ushort_t* pw1   = (ushort_t*)(ws + 80291840);   // 10,240
    ushort_t* pw234 = (ushort_t*)(ws + 80302080);   // 221,184

    // fused prep: pack input, pack weights, zero halos, zero emb accumulator
    prep_k<<<dim3(328), 256, 0, stream>>>(q, s, w1, w2, w3, w4,
                                          P0, pw1, pw234, P1, P2, P3, embv);

    // conv1: LDS fat-strip, 2 pooled rows/strip, 21x160 = 3360 blocks
    conv1_lds_k<<<dim3(21, 160), 256, 0, stream>>>(P0, pw1, g1, b1p, P1);

    // conv2: MT=2, RPB=3 strips, 7x160 = 1120 blocks, 4 blocks/CU
    conv2_k<<<dim3(7, 160), 256, 0, stream>>>(P1, pw234, g2, b2p, P2);
    // conv3: 2-wave, RPB=6, 4x160 = 640 blocks
    conv3_k<<<dim3(4, 160), 128, 0, stream>>>(P2, pw234 + 36864, g3, b3p, P3);
    // conv4: fused GAP -> atomicAdd into embv
    conv4_k<<<dim3(4, 160), 128, 0, stream>>>(
        P3, pw234 + 2 * 36864, g4, b4p, (ushort_t*)embv);

    relation_k<<<dim3(300), 64, 0, stream>>>(
        embv, fc1w, fc1b, fc2w, fc2b, fc3w, fc3b, out);
}

// Round 17
// 109.106 us; speedup vs baseline: 1.0575x; 1.0575x over previous
//
#include <hip/hip_runtime.h>
#include <math.h>

typedef unsigned short ushort_t;
typedef __attribute__((ext_vector_type(8))) short bf16x8;
typedef __attribute__((ext_vector_type(16))) float f32x16;

__device__ __forceinline__ ushort_t f2bf(float f) {
    unsigned u = __float_as_uint(f);
    u += 0x7fffu + ((u >> 16) & 1u);          // RNE
    return (ushort_t)(u >> 16);
}
__device__ __forceinline__ float bf2f(ushort_t h) {
    return __uint_as_float(((unsigned)h) << 16);
}

// ---------------------------------------------------------------------------
// Halo-zero helper for planar padded bf16 buffer [2][160][HP][HP][32].
// ---------------------------------------------------------------------------
template <int HP>
__device__ __forceinline__ void zero_halo(ushort_t* buf, int n, int t, int nthr)
{
    const size_t PSTR = (size_t)160 * HP * HP * 32;
    constexpr int W = HP - 2;
    constexpr int NB = 2 * HP + 2 * W;
    for (int j = t; j < 2 * NB; j += nthr) {
        const int pl = j / NB, i = j % NB;
        int yy, xx;
        if (i < HP)            { yy = 0;            xx = i; }
        else if (i < 2 * HP)   { yy = HP - 1;       xx = i - HP; }
        else if (i < 2*HP + W) { yy = i - 2*HP + 1; xx = 0; }
        else                   { yy = i - 2*HP - W + 1; xx = HP - 1; }
        uint4* p = (uint4*)(buf + pl * PSTR +
                            ((size_t)n * HP * HP + yy * HP + xx) * 32);
        const uint4 z = make_uint4(0u, 0u, 0u, 0u);
        p[0] = z; p[1] = z;
    }
}

// ---------------------------------------------------------------------------
// prep_k: fused input pack + weight pack + halo zeroing + embv zeroing.
//  b in [0,160): pack image; [160,167): weights; [167,327): halos P1,P2;
//  327: embv=0
// ---------------------------------------------------------------------------
__global__ __launch_bounds__(256) void prep_k(
    const float* __restrict__ q, const float* __restrict__ s,
    const float* __restrict__ w1, const float* __restrict__ w2,
    const float* __restrict__ w3, const float* __restrict__ w4,
    ushort_t* __restrict__ p0, ushort_t* __restrict__ pw1,
    ushort_t* __restrict__ pw234,
    ushort_t* __restrict__ P1, ushort_t* __restrict__ P2,
    float* __restrict__ embv)
{
    const int b = blockIdx.x, t = threadIdx.x;
    if (b < 160) {
        const int n = b;
        const float* src; int nn;
        if (n < 60) { src = q; nn = n; } else { src = s; nn = n - 60; }
        const float* img = src + (size_t)nn * 3 * 7056;
        for (int px = t; px < 7396; px += 256) {
            const int y = px / 86, x = px % 86;
            uint4 v = make_uint4(0u, 0u, 0u, 0u);
            if (y >= 1 && y <= 84 && x >= 1 && x <= 84) {
                const int o = (y - 1) * 84 + (x - 1);
                const unsigned c0 = f2bf(img[o]);
                const unsigned c1 = f2bf(img[7056 + o]);
                const unsigned c2 = f2bf(img[14112 + o]);
                v.x = c0 | (c1 << 16);
                v.y = c2;
            }
            *(uint4*)(p0 + ((size_t)n * 7396 + px) * 8) = v;
        }
    } else if (b < 167) {
        const int bw = b - 160;
        if (bw == 0) {
            for (int idx = t; idx < 5120; idx += 256) {
                const int sl = idx >> 10, rem = idx & 1023;
                const int co = rem >> 4, c = rem & 15;
                const int h = c >> 3, e = c & 7, tap = 2 * sl + h;
                float v = 0.f;
                if (tap < 9 && e < 3) v = w1[co * 27 + e * 9 + tap];
                pw1[idx] = f2bf(v);
            }
        } else {
            const int l = (bw - 1) >> 1, pass = (bw - 1) & 1;
            const float* w = (l == 0) ? w2 : (l == 1) ? w3 : w4;
            ushort_t* dst = pw234 + l * 36864 + pass * 18432;
            for (int idx = t; idx < 18432; idx += 256) {
                const int c  = idx & 7;
                const int co = (idx >> 3) & 63;
                const int h  = (idx >> 9) & 1;
                const int kl = (idx >> 10) & 1;
                const int tap = idx >> 11;
                const int ci = pass * 32 + kl * 16 + h * 8 + c;
                dst[idx] = f2bf(w[co * 576 + ci * 9 + tap]);
            }
        }
    } else if (b < 327) {
        const int n = b - 167;
        zero_halo<44>(P1, n, t, 256);
        zero_halo<23>(P2, n, t, 256);
    } else {
        for (int i = t; i < 2560; i += 256)
            ((uint4*)embv)[i] = make_uint4(0u, 0u, 0u, 0u);
    }
}

// ---------------------------------------------------------------------------
// conv1 LDS fat-strip MFMA (unchanged, proven).
// ---------------------------------------------------------------------------
__global__ __launch_bounds__(256, 2) void conv1_lds_k(
    const ushort_t* __restrict__ p0, const ushort_t* __restrict__ pw1,
    const float* __restrict__ gg, const float* __restrict__ bb,
    ushort_t* __restrict__ outp)
{
    constexpr int ROWB = 86 * 16 + 16;   // 1392 B
    constexpr int R = 6;
    constexpr int PXB = 84;              // pooled px per strip
    constexpr size_t PLANE1 = (size_t)160 * 1936 * 32;

    __shared__ __align__(16) char alds[R * ROWB];
    __shared__ __align__(16) char blds[10240];

    const int tid = threadIdx.x, wv = tid >> 6, lane = tid & 63;
    const int l31 = lane & 31, h = lane >> 5;
    const int s = blockIdx.x, n = blockIdx.y;
    const int row0 = 4 * s;

    int abase[3];
#pragma unroll
    for (int t = 0; t < 3; ++t) {
        const int ml = wv * 96 + t * 32 + l31;
        int pp = ml >> 2; if (pp > PXB - 1) pp = PXB - 1;
        const int qd = ml & 3;
        const int p = PXB * s + pp;
        const int pr = p / 42, pc = p % 42;
        const int yl = 2 * (pr - 2 * s) + (qd >> 1);
        const int xl = 2 * pc + (qd & 1);
        abase[t] = yl * ROWB + xl * 16;
    }
    int boff[2];
#pragma unroll
    for (int nt = 0; nt < 2; ++nt) boff[nt] = (nt * 32 + l31) * 32 + h * 16;

    {
        const uint4* src = (const uint4*)(p0 + (size_t)n * 7396 * 8);
        for (int i = tid; i < R * 86; i += 256) {
            const int y = i / 86, x = i - y * 86;
            *(uint4*)(alds + y * ROWB + x * 16) = src[(row0 + y) * 86 + x];
        }
    }
    for (int i = tid; i < 640; i += 256)
        ((uint4*)blds)[i] = ((const uint4*)pw1)[i];

    f32x16 acc[3][2];
#pragma unroll
    for (int t = 0; t < 3; ++t)
#pragma unroll
        for (int nt = 0; nt < 2; ++nt)
#pragma unroll
            for (int r = 0; r < 16; ++r) acc[t][nt][r] = 0.f;

    __syncthreads();

#pragma unroll
    for (int st = 0; st < 5; ++st) {
        int tap = 2 * st + h;
        if (tap > 8) tap = 8;           // B is zero there; data unused
        const int imm = (tap / 3) * ROWB + (tap % 3) * 16;
        const bf16x8 a0 = *(const bf16x8*)(alds + abase[0] + imm);
        const bf16x8 a1 = *(const bf16x8*)(alds + abase[1] + imm);
        const bf16x8 a2 = *(const bf16x8*)(alds + abase[2] + imm);
#pragma unroll
        for (int nt = 0; nt < 2; ++nt) {
            const bf16x8 b = *(const bf16x8*)(blds + st * 2048 + boff[nt]);
            acc[0][nt] = __builtin_amdgcn_mfma_f32_32x32x16_bf16(
                a0, b, acc[0][nt], 0, 0, 0);
            acc[1][nt] = __builtin_amdgcn_mfma_f32_32x32x16_bf16(
                a1, b, acc[1][nt], 0, 0, 0);
            acc[2][nt] = __builtin_amdgcn_mfma_f32_32x32x16_bf16(
                a2, b, acc[2][nt], 0, 0, 0);
        }
    }

    float gv2[2], bv2[2];
#pragma unroll
    for (int nt = 0; nt < 2; ++nt) {
        gv2[nt] = gg[nt * 32 + l31];
        bv2[nt] = bb[nt * 32 + l31];
    }
#pragma unroll
    for (int t = 0; t < 3; ++t) {
#pragma unroll
        for (int g = 0; g < 4; ++g) {
            const int mbase = wv * 96 + t * 32 + 8 * g + 4 * h;
            const int pp = mbase >> 2;
            if (pp >= PXB) continue;
            const int p = PXB * s + pp;
            const int pr = p / 42, pc = p % 42;
            ushort_t* dpix =
                outp + ((size_t)n * 1936 + (pr + 1) * 44 + (pc + 1)) * 32 + l31;
#pragma unroll
            for (int nt = 0; nt < 2; ++nt) {
                float mx = 0.f;   // ReLU lower bound
#pragma unroll
                for (int qd = 0; qd < 4; ++qd)
                    mx = fmaxf(mx, fmaf(acc[t][nt][4 * g + qd], gv2[nt], bv2[nt]));
                dpix[nt * PLANE1] = f2bf(mx);
            }
        }
    }
}

// ---------------------------------------------------------------------------
// conv2: LDS-A + ring-4 global-B MFMA (R14/R15 proven structure).
// Affine+ReLU+2x2pool -> planar padded [2][160][23][23][32].
// ---------------------------------------------------------------------------
__global__ __launch_bounds__(256, 4) void conv2_k(
    const ushort_t* __restrict__ act, const ushort_t* __restrict__ pkw,
    const float* __restrict__ gg, const float* __restrict__ bb,
    ushort_t* __restrict__ outp)
{
    constexpr int HINP = 44, RPB = 3, WAVES = 4, MT = 2;
    constexpr int NTHR = WAVES * 64;
    constexpr int PXB  = 21 * RPB;
    constexpr int R    = 2 * RPB + 2;
    constexpr int ROWB = HINP * 80;
    const size_t APLANE = (size_t)160 * HINP * HINP * 32;
    constexpr size_t OPLANE = (size_t)160 * 529 * 32;

    __shared__ __align__(16) char alds[R * ROWB];

    const int tid = threadIdx.x, wv = tid >> 6, lane = tid & 63;
    const int l31 = lane & 31, h = lane >> 5;
    const int s = blockIdx.x, n = blockIdx.y;
    const int row0 = 2 * RPB * s;

    int abase[MT];
#pragma unroll
    for (int t = 0; t < MT; ++t) {
        const int ml = wv * (MT * 32) + t * 32 + l31;
        int pp = ml >> 2; if (pp > PXB - 1) pp = PXB - 1;
        int p = PXB * s + pp; if (p > 440) p = 440;
        const int qd = ml & 3;
        const int yl = 2 * (p / 21 - RPB * s) + (qd >> 1);
        const int xl = 2 * (p % 21) + (qd & 1);
        abase[t] = yl * ROWB + xl * 80 + h * 16;
    }
    int boff[2];
#pragma unroll
    for (int nt = 0; nt < 2; ++nt) boff[nt] = h * 1024 + (nt * 32 + l31) * 16;

    f32x16 acc[MT][2];
#pragma unroll
    for (int t = 0; t < MT; ++t)
#pragma unroll
        for (int nt = 0; nt < 2; ++nt)
#pragma unroll
            for (int r = 0; r < 16; ++r) acc[t][nt][r] = 0.f;

    bf16x8 br[4][2];

#define B_LD(S, SLOT)                                                      \
    {                                                                      \
        br[SLOT][0] = *(const bf16x8*)(bg + (S)*2048 + boff[0]);           \
        br[SLOT][1] = *(const bf16x8*)(bg + (S)*2048 + boff[1]);           \
    }

    for (int ph = 0; ph < 2; ++ph) {
        const char* bg = (const char*)pkw + ph * 36864;
        B_LD(0, 0) B_LD(1, 1) B_LD(2, 2) B_LD(3, 3)

        if (ph) __syncthreads();
        {
            const uint4* src = (const uint4*)(act +
                (ph * APLANE + (size_t)n * HINP * HINP * 32));
            for (int p = tid; p < R * HINP; p += NTHR) {
                const int y = p / HINP, x = p - y * HINP;
                const int row = min(row0 + y, HINP - 1);
                const uint4* sp = src + ((size_t)row * HINP + x) * 4;
                const uint4 c0 = sp[0], c1 = sp[1], c2 = sp[2], c3 = sp[3];
                char* d = alds + y * ROWB + x * 80;
                *(uint4*)(d)      = c0;
                *(uint4*)(d + 16) = c1;
                *(uint4*)(d + 32) = c2;
                *(uint4*)(d + 48) = c3;
            }
        }
        __syncthreads();

#pragma unroll
        for (int st = 0; st < 18; ++st) {
            const int sl = st & 3;
            const int tap = st >> 1, kl = st & 1;
            const int imm = (tap / 3) * ROWB + (tap % 3) * 80 + kl * 32;
            const bf16x8 a0 = *(const bf16x8*)(alds + abase[0] + imm);
            const bf16x8 a1 = *(const bf16x8*)(alds + abase[1] + imm);
            const bf16x8 b0 = br[sl][0];
            const bf16x8 b1 = br[sl][1];
            if (st < 14) B_LD(st + 4, sl)
            acc[0][0] = __builtin_amdgcn_mfma_f32_32x32x16_bf16(
                a0, b0, acc[0][0], 0, 0, 0);
            acc[1][0] = __builtin_amdgcn_mfma_f32_32x32x16_bf16(
                a1, b0, acc[1][0], 0, 0, 0);
            acc[0][1] = __builtin_amdgcn_mfma_f32_32x32x16_bf16(
                a0, b1, acc[0][1], 0, 0, 0);
            acc[1][1] = __builtin_amdgcn_mfma_f32_32x32x16_bf16(
                a1, b1, acc[1][1], 0, 0, 0);
        }
    }
#undef B_LD

    float gv2[2], bv2[2];
#pragma unroll
    for (int nt = 0; nt < 2; ++nt) {
        gv2[nt] = gg[nt * 32 + l31];
        bv2[nt] = bb[nt * 32 + l31];
    }
#pragma unroll
    for (int t = 0; t < MT; ++t) {
#pragma unroll
        for (int g = 0; g < 4; ++g) {
            const int mbase = wv * (MT * 32) + t * 32 + 8 * g + 4 * h;
            const int pp = mbase >> 2;
            const int p_img = PXB * s + pp;
            if (pp >= PXB || p_img >= 441) continue;
            const int py = p_img / 21, px = p_img % 21;
            ushort_t* dpix = outp +
                ((size_t)n * 529 + (py + 1) * 23 + (px + 1)) * 32 + l31;
#pragma unroll
            for (int nt = 0; nt < 2; ++nt) {
                float mx = 0.f;
#pragma unroll
                for (int qd = 0; qd < 4; ++qd)
                    mx = fmaxf(mx,
                               fmaf(acc[t][nt][4 * g + qd], gv2[nt], bv2[nt]));
                dpix[nt * OPLANE] = f2bf(mx);
            }
        }
    }
}

// ---------------------------------------------------------------------------
// conv34_k: FUSED conv3+conv4, one block per image (8 waves, 512 thr).
// conv3: stage P2 plane-by-plane into alds, K-loop (B ring-4 global),
//        epilogue -> mid LDS (padded planar [2][23][23][32], 80B/px, halo 0).
// conv4: K-loop reads A straight from mid (both planes), B ring-4 global,
//        fused GAP epilogue -> atomicAdd f32 emb.
// LDS = 42,320 + 84,640 = 126,960 B -> 1 block/CU.
// ---------------------------------------------------------------------------
__global__ __launch_bounds__(512, 2) void conv34_k(
    const ushort_t* __restrict__ P2, const ushort_t* __restrict__ pkw3,
    const ushort_t* __restrict__ pkw4,
    const float* __restrict__ g3, const float* __restrict__ b3,
    const float* __restrict__ g4, const float* __restrict__ b4,
    float* __restrict__ embv)
{
    constexpr int ROWB = 23 * 80;              // 1840 B
    constexpr int PLB  = 23 * ROWB;            // 42,320 B per plane
    const size_t APLANE = (size_t)160 * 529 * 32;

    __shared__ __align__(16) char alds[PLB];       // conv3 input, one plane
    __shared__ __align__(16) char mid[2 * PLB];    // conv3 out / conv4 in

    const int tid = threadIdx.x, wv = tid >> 6, lane = tid & 63;
    const int l31 = lane & 31, h = lane >> 5;
    const int n = blockIdx.x;

    int abase[2];
#pragma unroll
    for (int t = 0; t < 2; ++t) {
        int ml = wv * 64 + t * 32 + l31;
        if (ml > 440) ml = 440;
        abase[t] = (ml / 21) * ROWB + (ml % 21) * 80 + h * 16;
    }
    int boff[2];
#pragma unroll
    for (int nt = 0; nt < 2; ++nt) boff[nt] = h * 1024 + (nt * 32 + l31) * 16;

    f32x16 acc[2][2];
#pragma unroll
    for (int t = 0; t < 2; ++t)
#pragma unroll
        for (int nt = 0; nt < 2; ++nt)
#pragma unroll
            for (int r = 0; r < 16; ++r) acc[t][nt][r] = 0.f;

    bf16x8 br[4][2];

#define B_LD(S, SLOT)                                                      \
    {                                                                      \
        br[SLOT][0] = *(const bf16x8*)(bg + (S)*2048 + boff[0]);           \
        br[SLOT][1] = *(const bf16x8*)(bg + (S)*2048 + boff[1]);           \
    }

    // ================= conv3 =================
    for (int ph = 0; ph < 2; ++ph) {
        const char* bg = (const char*)pkw3 + ph * 36864;
        B_LD(0, 0) B_LD(1, 1) B_LD(2, 2) B_LD(3, 3)

        if (ph) __syncthreads();
        {
            const uint4* src = (const uint4*)(P2 + ph * APLANE +
                                              (size_t)n * 529 * 32);
            for (int p = tid; p < 529; p += 512) {
                const int y = p / 23, x = p - y * 23;
                const uint4* sp = src + (size_t)p * 4;
                const uint4 c0 = sp[0], c1 = sp[1], c2 = sp[2], c3 = sp[3];
                char* d = alds + y * ROWB + x * 80;
                *(uint4*)(d)      = c0;
                *(uint4*)(d + 16) = c1;
                *(uint4*)(d + 32) = c2;
                *(uint4*)(d + 48) = c3;
            }
        }
        __syncthreads();

#pragma unroll
        for (int st = 0; st < 18; ++st) {
            const int sl = st & 3;
            const int tap = st >> 1, kl = st & 1;
            const int imm = (tap / 3) * ROWB + (tap % 3) * 80 + kl * 32;
            const bf16x8 a0 = *(const bf16x8*)(alds + abase[0] + imm);
            const bf16x8 a1 = *(const bf16x8*)(alds + abase[1] + imm);
            const bf16x8 b0 = br[sl][0];
            const bf16x8 b1 = br[sl][1];
            if (st < 14) B_LD(st + 4, sl)
            acc[0][0] = __builtin_amdgcn_mfma_f32_32x32x16_bf16(
                a0, b0, acc[0][0], 0, 0, 0);
            acc[1][0] = __builtin_amdgcn_mfma_f32_32x32x16_bf16(
                a1, b0, acc[1][0], 0, 0, 0);
            acc[0][1] = __builtin_amdgcn_mfma_f32_32x32x16_bf16(
                a0, b1, acc[0][1], 0, 0, 0);
            acc[1][1] = __builtin_amdgcn_mfma_f32_32x32x16_bf16(
                a1, b1, acc[1][1], 0, 0, 0);
        }
    }

    // conv3 epilogue -> mid (interior) + halo zero
    {
        float gv2[2], bv2[2];
#pragma unroll
        for (int nt = 0; nt < 2; ++nt) {
            gv2[nt] = g3[nt * 32 + l31];
            bv2[nt] = b3[nt * 32 + l31];
        }
        // zero mid halo: 88 border px per plane
        for (int j = tid; j < 176; j += 512) {
            const int pl = j / 88, i = j % 88;
            int yy, xx;
            if (i < 23)       { yy = 0;          xx = i; }
            else if (i < 46)  { yy = 22;         xx = i - 23; }
            else if (i < 67)  { yy = i - 46 + 1; xx = 0; }
            else              { yy = i - 67 + 1; xx = 22; }
            char* d = mid + pl * PLB + yy * ROWB + xx * 80;
            const uint4 z = make_uint4(0u, 0u, 0u, 0u);
            *(uint4*)(d)      = z;
            *(uint4*)(d + 16) = z;
            *(uint4*)(d + 32) = z;
            *(uint4*)(d + 48) = z;
        }
#pragma unroll
        for (int t = 0; t < 2; ++t) {
#pragma unroll
            for (int r = 0; r < 16; ++r) {
                const int mloc = wv * 64 + t * 32 + (r & 3) + 8 * (r >> 2) + 4 * h;
                if (mloc >= 441) continue;
                const int y = mloc / 21, x = mloc % 21;
#pragma unroll
                for (int nt = 0; nt < 2; ++nt) {
                    const float v =
                        fmaxf(fmaf(acc[t][nt][r], gv2[nt], bv2[nt]), 0.f);
                    *(ushort_t*)(mid + nt * PLB + (y + 1) * ROWB +
                                 (x + 1) * 80 + l31 * 2) = f2bf(v);
                }
            }
        }
    }
    __syncthreads();

    // ================= conv4 =================
#pragma unroll
    for (int t = 0; t < 2; ++t)
#pragma unroll
        for (int nt = 0; nt < 2; ++nt)
#pragma unroll
            for (int r = 0; r < 16; ++r) acc[t][nt][r] = 0.f;

    for (int ph = 0; ph < 2; ++ph) {
        const char* bg = (const char*)pkw4 + ph * 36864;
        const char* am = mid + ph * PLB;
        B_LD(0, 0) B_LD(1, 1) B_LD(2, 2) B_LD(3, 3)
#pragma unroll
        for (int st = 0; st < 18; ++st) {
            const int sl = st & 3;
            const int tap = st >> 1, kl = st & 1;
            const int imm = (tap / 3) * ROWB + (tap % 3) * 80 + kl * 32;
            const bf16x8 a0 = *(const bf16x8*)(am + abase[0] + imm);
            const bf16x8 a1 = *(const bf16x8*)(am + abase[1] + imm);
            const bf16x8 b0 = br[sl][0];
            const bf16x8 b1 = br[sl][1];
            if (st < 14) B_LD(st + 4, sl)
            acc[0][0] = __builtin_amdgcn_mfma_f32_32x32x16_bf16(
                a0, b0, acc[0][0], 0, 0, 0);
            acc[1][0] = __builtin_amdgcn_mfma_f32_32x32x16_bf16(
                a1, b0, acc[1][0], 0, 0, 0);
            acc[0][1] = __builtin_amdgcn_mfma_f32_32x32x16_bf16(
                a0, b1, acc[0][1], 0, 0, 0);
            acc[1][1] = __builtin_amdgcn_mfma_f32_32x32x16_bf16(
                a1, b1, acc[1][1], 0, 0, 0);
        }
    }
#undef B_LD

    // conv4 epilogue: fused GAP -> atomicAdd f32 emb
    {
        float gv2[2], bv2[2];
#pragma unroll
        for (int nt = 0; nt < 2; ++nt) {
            gv2[nt] = g4[nt * 32 + l31];
            bv2[nt] = b4[nt * 32 + l31];
        }
#pragma unroll
        for (int nt = 0; nt < 2; ++nt) {
            float sum = 0.f;
#pragma unroll
            for (int t = 0; t < 2; ++t) {
#pragma unroll
                for (int r = 0; r < 16; ++r) {
                    const int mloc = wv * 64 + t * 32 +
                                     (r & 3) + 8 * (r >> 2) + 4 * h;
                    if (mloc < 441)
                        sum += fmaxf(fmaf(acc[t][nt][r], gv2[nt], bv2[nt]), 0.f);
                }
            }
            atomicAdd(&embv[(size_t)n * 64 + nt * 32 + l31],
                      sum * (1.f / 441.f));
        }
    }
}

// ---------------------------------------------------------------------------
// Relation head.
// ---------------------------------------------------------------------------
__global__ __launch_bounds__(64) void relation_k(
    const float* __restrict__ emb,
    const float* __restrict__ fc1w, const float* __restrict__ fc1b,
    const float* __restrict__ fc2w, const float* __restrict__ fc2b,
    const float* __restrict__ fc3w, const float* __restrict__ fc3b,
    float* __restrict__ out)
{
    const int idx = blockIdx.x;
    const int w = idx % 5;
    const int bq = idx / 5;
    const int b = bq / 15;
    const int t = threadIdx.x;

    __shared__ float dif[64], h1v[64], h2v[32];
    const float qv = emb[(size_t)bq * 64 + t];

    float ssum = 0.f;
    for (int s = 0; s < 5; ++s) {
        const int simg = 60 + ((b * 5 + w) * 5 + s);
        __syncthreads();
        dif[t] = fabsf(qv - emb[(size_t)simg * 64 + t]);
        __syncthreads();
        float a = fc1b[t];
        for (int d = 0; d < 64; ++d) a = fmaf(fc1w[t * 64 + d], dif[d], a);
        a = fmaxf(a, 0.f);
        __syncthreads();
        h1v[t] = a;
        __syncthreads();
        if (t < 32) {
            float h = fc2b[t];
            for (int d = 0; d < 64; ++d) h = fmaf(fc2w[t * 64 + d], h1v[d], h);
            h2v[t] = fmaxf(h, 0.f);
        }
        __syncthreads();
        float p = (t < 32) ? fc3w[t] * h2v[t] : 0.f;
#pragma unroll
        for (int off = 32; off > 0; off >>= 1) p += __shfl_down(p, off);
        if (t == 0) {
            const float z = p + fc3b[0];
            ssum += 1.f / (1.f + expf(-z));
        }
    }
    if (t == 0) out[idx] = ssum * 0.2f;
}

// ---------------------------------------------------------------------------
extern "C" void kernel_launch(void* const* d_in, const int* in_sizes, int n_in,
                              void* d_out, int out_size, void* d_ws, size_t ws_size,
                              hipStream_t stream)
{
    const float* q    = (const float*)d_in[0];
    const float* s    = (const float*)d_in[1];
    const float* w1   = (const float*)d_in[2];
    const float* g1   = (const float*)d_in[3];
    const float* b1p  = (const float*)d_in[4];
    const float* w2   = (const float*)d_in[5];
    const float* g2   = (const float*)d_in[6];
    const float* b2p  = (const float*)d_in[7];
    const float* w3   = (const float*)d_in[8];
    const float* g3   = (const float*)d_in[9];
    const float* b3p  = (const float*)d_in[10];
    const float* w4   = (const float*)d_in[11];
    const float* g4   = (const float*)d_in[12];
    const float* b4p  = (const float*)d_in[13];
    const float* fc1w = (const float*)d_in[14];
    const float* fc1b = (const float*)d_in[15];
    const float* fc2w = (const float*)d_in[16];
    const float* fc2b = (const float*)d_in[17];
    const float* fc3w = (const float*)d_in[18];
    const float* fc3b = (const float*)d_in[19];
    float* out = (float*)d_out;

    char* ws = (char*)d_ws;
    ushort_t* P0    = (ushort_t*)(ws + 0);          // 18,933,760
    ushort_t* P1    = (ushort_t*)(ws + 18933760);   // 39,649,280
    ushort_t* P2    = (ushort_t*)(ws + 58583040);   // 10,833,920
    float*    embv  = (float*)   (ws + 69416960);   // 40,960 (f32 accumulator)
    ushort_t* pw1   = (ushort_t*)(ws + 69457920);   // 10,240
    ushort_t* pw234 = (ushort_t*)(ws + 69468160);   // 221,184

    // fused prep: pack input, pack weights, zero halos, zero emb accumulator
    prep_k<<<dim3(328), 256, 0, stream>>>(q, s, w1, w2, w3, w4,
                                          P0, pw1, pw234, P1, P2, embv);

    // conv1: LDS fat-strip, 2 pooled rows/strip, 21x160 = 3360 blocks
    conv1_lds_k<<<dim3(21, 160), 256, 0, stream>>>(P0, pw1, g1, b1p, P1);

    // conv2: MT=2, RPB=3 strips, 7x160 = 1120 blocks
    conv2_k<<<dim3(7, 160), 256, 0, stream>>>(P1, pw234, g2, b2p, P2);

    // conv3+conv4 fused, one block per image, GAP -> embv
    conv34_k<<<dim3(160), 512, 0, stream>>>(
        P2, pw234 + 36864, pw234 + 2 * 36864, g3, b3p, g4, b4p, embv);

    relation_k<<<dim3(300), 64, 0, stream>>>(
        embv, fc1w, fc1b, fc2w, fc2b, fc3w, fc3b, out);
}